// Round 11
// baseline (451.921 us; speedup 1.0000x reference)
//
#include <hip/hip_runtime.h>

#define B_ 32
#define C_ 512
#define HW_ 3136
#define KF_ 512
#define KM_ 48
#define NCL_ 5

typedef __attribute__((ext_vector_type(8))) short short8;
typedef __attribute__((ext_vector_type(4))) short short4v;
typedef __attribute__((ext_vector_type(4))) float floatx4;
typedef unsigned int u32;
typedef u32 __attribute__((address_space(1))) gu32;
typedef u32 __attribute__((address_space(3))) lu32;

__device__ __forceinline__ unsigned short f2bf(float f) {
    union { float f; unsigned u; } v; v.f = f;
    unsigned r = v.u + 0x7FFFu + ((v.u >> 16) & 1u);
    return (unsigned short)(r >> 16);
}
__device__ __forceinline__ void gl2lds16(const void* g, void* l) {
    __builtin_amdgcn_global_load_lds((const gu32*)g, (lu32*)l, 16, 0, 0);
}

// ---- K0: normalize conv weights -> bf16 wn; clutter -> ck fp32 (clip + L1)
__global__ __launch_bounds__(64) void prep_kernel(const float* __restrict__ w,
                                                  const float* __restrict__ cl,
                                                  unsigned short* __restrict__ wn,
                                                  float* __restrict__ ck) {
    int bid = blockIdx.x, t = threadIdx.x;
    if (bid < KF_) {
        const float* row = w + (size_t)bid * C_;
        float ss = 0.f;
        float x[8];
#pragma unroll
        for (int j = 0; j < 8; ++j) { x[j] = row[t * 8 + j]; ss += x[j] * x[j]; }
        for (int m = 32; m >= 1; m >>= 1) ss += __shfl_xor(ss, m);
        float inv = 1.f / sqrtf(ss);
#pragma unroll
        for (int j = 0; j < 8; ++j) wn[(size_t)bid * C_ + t * 8 + j] = f2bf(x[j] * inv);
    } else {
        int n = bid - KF_;
        if (n >= NCL_) return;
        const float* row = cl + (size_t)n * KF_;
        float s = 0.f;
        float v[8];
#pragma unroll
        for (int j = 0; j < 8; ++j) {
            float x = row[t * 8 + j];
            x = fminf(fmaxf(x, 0.f), 1.f);
            v[j] = x; s += x;
        }
        for (int m = 32; m >= 1; m >>= 1) s += __shfl_xor(s, m);
        float inv = 1.f / fmaxf(s, 1e-12f);
#pragma unroll
        for (int j = 0; j < 8; ++j) ck[(size_t)n * KF_ + t * 8 + j] = v[j] * inv;
    }
}

// ---- K1: streaming pass: vgg -> xnt (raw bf16, [b*HW+p][c]), invn, vgg copy
__global__ __launch_bounds__(512) void xprep_kernel(const float* __restrict__ vgg,
                                                    unsigned short* __restrict__ xnt,
                                                    float* __restrict__ invn,
                                                    float* __restrict__ out_vgg,
                                                    int write_vgg) {
    int pt = blockIdx.x, b = blockIdx.y;
    int tid = threadIdx.x;
    int px = tid & 63, cq = tid >> 6;
    __shared__ __align__(16) unsigned short tile[64][512];
    __shared__ float ssp[8][64];
    const float* vcol = vgg + (size_t)b * C_ * HW_ + pt * 64 + px;
    float* ovcol = out_vgg + (size_t)b * C_ * HW_ + pt * 64 + px;

    float ss = 0.f;
#pragma unroll
    for (int j = 0; j < 16; ++j) {
        int c0 = cq * 64 + j * 4;
        float x0 = vcol[(size_t)(c0 + 0) * HW_];
        float x1 = vcol[(size_t)(c0 + 1) * HW_];
        float x2 = vcol[(size_t)(c0 + 2) * HW_];
        float x3 = vcol[(size_t)(c0 + 3) * HW_];
        ss += x0 * x0 + x1 * x1 + x2 * x2 + x3 * x3;
        short4v pk;
        pk[0] = (short)f2bf(x0); pk[1] = (short)f2bf(x1);
        pk[2] = (short)f2bf(x2); pk[3] = (short)f2bf(x3);
        *(short4v*)&tile[px][c0] = pk;
        if (write_vgg) {
            ovcol[(size_t)(c0 + 0) * HW_] = x0;
            ovcol[(size_t)(c0 + 1) * HW_] = x1;
            ovcol[(size_t)(c0 + 2) * HW_] = x2;
            ovcol[(size_t)(c0 + 3) * HW_] = x3;
        }
    }
    ssp[cq][px] = ss;
    __syncthreads();
    if (tid < 64) {
        float s = 0.f;
#pragma unroll
        for (int q = 0; q < 8; ++q) s += ssp[q][tid];
        float n = sqrtf(s);
        invn[(size_t)b * HW_ + pt * 64 + tid] = (n == 0.f) ? 1.f : 1.f / n;
    }
    __syncthreads();
    int row = tid >> 3, ch = tid & 7;
    unsigned short* orow = xnt + ((size_t)b * HW_ + pt * 64 + row) * 512;
#pragma unroll
    for (int j = 0; j < 8; ++j) {
        int c8 = (ch + 8 * j) * 8;
        *(short8*)(orow + c8) = *(const short8*)&tile[row][c8];
    }
}

// ---- K2: GEMM act = exp(30*(xnt.wn)*invn), counted-vmcnt dbuf + bg partials.
__global__ __launch_bounds__(512) void gemm_act_kernel(const unsigned short* __restrict__ xnt,
                                                       const unsigned short* __restrict__ wn,
                                                       const float* __restrict__ invn,
                                                       const float* __restrict__ ck,
                                                       unsigned short* __restrict__ act,
                                                       float* __restrict__ bgacc) {
    int wg = blockIdx.x;
    int swz = (wg & 7) * 392 + (wg >> 3);   // 3136 = 8*392, bijective
    int pt = swz >> 2, ft = swz & 3;
    int tid = threadIdx.x, lane = tid & 63;
    int wid = tid >> 6;
    int li = lane & 15, q = lane >> 4;
    int wm = wid & 1, wq = wid >> 1;

    __shared__ __align__(16) unsigned short a_lds[2][128 * 64];
    __shared__ __align__(16) unsigned short b_lds[2][128 * 64];
    __shared__ float inv_l[128];
    __shared__ float ck_l[NCL_ * KF_];
    __shared__ float bga_l[128 * NCL_];
    if (tid < 128) inv_l[tid] = invn[(size_t)pt * 128 + tid];
    for (int i = tid; i < NCL_ * KF_; i += 512) ck_l[i] = ck[i];
    for (int i = tid; i < 128 * NCL_; i += 512) bga_l[i] = 0.f;

    const unsigned short* ga = wn + ((size_t)ft * 128 + (tid >> 3)) * 512 + (tid & 7) * 8;
    const unsigned short* gb = xnt + ((size_t)pt * 128 + (tid >> 3)) * 512 + (tid & 7) * 8;
    int ldst = tid * 8;

    floatx4 acc[4][2] = {};

#pragma unroll
    for (int i = 0; i < 2; ++i) {
        gl2lds16(ga + (size_t)i * 64 * 512, &a_lds[0][ldst + i * 4096]);
        gl2lds16(gb + (size_t)i * 64 * 512, &b_lds[0][ldst + i * 4096]);
    }

#pragma unroll 1
    for (int s = 0; s < 8; ++s) {
        __builtin_amdgcn_s_barrier();   // WAR
        if (s < 7) {
            int nb = (s + 1) & 1;
#pragma unroll
            for (int i = 0; i < 2; ++i) {
                gl2lds16(ga + (size_t)i * 64 * 512 + (s + 1) * 64, &a_lds[nb][ldst + i * 4096]);
                gl2lds16(gb + (size_t)i * 64 * 512 + (s + 1) * 64, &b_lds[nb][ldst + i * 4096]);
            }
            asm volatile("s_waitcnt vmcnt(4)" ::: "memory");
        } else {
            asm volatile("s_waitcnt vmcnt(0)" ::: "memory");
        }
        __builtin_amdgcn_sched_barrier(0);
        __builtin_amdgcn_s_barrier();   // RAW
        int buf = s & 1;
#pragma unroll
        for (int k2 = 0; k2 < 2; ++k2) {
            short8 af[4], bfr[2];
#pragma unroll
            for (int i = 0; i < 4; ++i)
                af[i] = *(const short8*)&a_lds[buf][(wm * 64 + i * 16 + li) * 64 + k2 * 32 + q * 8];
#pragma unroll
            for (int j = 0; j < 2; ++j)
                bfr[j] = *(const short8*)&b_lds[buf][(wq * 32 + j * 16 + li) * 64 + k2 * 32 + q * 8];
#pragma unroll
            for (int i = 0; i < 4; ++i)
#pragma unroll
                for (int j = 0; j < 2; ++j)
                    acc[i][j] = __builtin_amdgcn_mfma_f32_16x16x32_bf16(af[i], bfr[j], acc[i][j], 0, 0, 0);
        }
    }

    // epilogue: scale, exp, store act; bg partials via ck-dot
#pragma unroll
    for (int j = 0; j < 2; ++j) {
        int px = wq * 32 + j * 16 + li;
        float inv = inv_l[px];
        size_t row_g = (size_t)pt * 128 + px;
        float bp[NCL_] = {0.f, 0.f, 0.f, 0.f, 0.f};
#pragma unroll
        for (int i = 0; i < 4; ++i) {
            int chn = ft * 8 + wm * 4 + i;
            int f_g = ft * 128 + wm * 64 + i * 16 + q * 4;
            short4v pk;
            float av[4];
#pragma unroll
            for (int r = 0; r < 4; ++r) {
                float cv = acc[i][j][r] * inv;
                float a = cv > 0.f ? __expf(30.f * cv) : 0.f;
                av[r] = a;
                pk[r] = (short)f2bf(a);
            }
            *(short4v*)(act + ((size_t)chn * 100352 + row_g) * 16 + q * 4) = pk;
#pragma unroll
            for (int n = 0; n < NCL_; ++n)
                bp[n] += av[0] * ck_l[n * KF_ + f_g] + av[1] * ck_l[n * KF_ + f_g + 1] +
                         av[2] * ck_l[n * KF_ + f_g + 2] + av[3] * ck_l[n * KF_ + f_g + 3];
        }
#pragma unroll
        for (int n = 0; n < NCL_; ++n) {
            float v = bp[n];
            v += __shfl_xor(v, 16);
            v += __shfl_xor(v, 32);
            if (q == 0) atomicAdd(&bga_l[px * NCL_ + n], v);
        }
    }
    __syncthreads();
    if (tid < 128) {
        size_t row_g = (size_t)pt * 128 + tid;
#pragma unroll
        for (int n = 0; n < NCL_; ++n)
            atomicAdd(&bgacc[row_g * 8 + n], bga_l[tid * NCL_ + n]);
    }
}

// ---- K4 v4 (fg3): px-tile 64, m-split 3, mm fp32 direct, k8 double-buffer.
// grid 168 = 8 xcd x 7 ptq x 3 mg (trio shares act tile in one XCD's L2).
// LDS per buffer: act [b32][slot64][16B] = 32 KB (slot = px ^ (b&7));
//                 mm  [m16][k8][slot16*16B] fp32 = 32 KB (slot = pxgrp ^ m).
__global__ __launch_bounds__(512) void fg3_kernel(const unsigned short* __restrict__ act,
                                                  const float* __restrict__ mm,
                                                  const float* __restrict__ bgacc,
                                                  float* __restrict__ pm) {
    __shared__ __align__(16) unsigned char L[145408];
    float* bgs    = (float*)(L + 131072);   // [32][64]
    float* csum_s = (float*)(L + 139264);   // [16][64]
    float* pms    = (float*)(L + 143360);   // [16][32]

    int bid = blockIdx.x;
    int xcd = bid & 7, rest = bid >> 3;
    int mg = rest % 3, ptq = rest / 3;
    int pt = xcd + 8 * ptq;
    if (pt >= 49) return;
    int px0 = pt * 64;
    int m0 = mg * 16;

    int tid = threadIdx.x;
    int lane = tid & 63, w = tid >> 6;
    int li = lane & 15, q = lane >> 4;
    int w8 = w * 8;

    pms[tid & 511] = 0.f;
    for (int i = tid; i < 2048; i += 512) {
        int b = i >> 6, p = i & 63;
        const float* bgp = bgacc + ((size_t)b * HW_ + px0 + p) * 8;
        float mx = -1e30f;
#pragma unroll
        for (int n = 0; n < NCL_; ++n) mx = fmaxf(mx, logf(bgp[n] * 0.6f + 1e-10f));
        bgs[i] = mx;
    }

    // staging source/dest precompute: 4 act instrs (b = w*4+t), 4 mm instrs (m=w*2+u, kq)
    const unsigned short* srcA[4];
    int dA[4];
#pragma unroll
    for (int t = 0; t < 4; ++t) {
        int b = w * 4 + t;
        srcA[t] = act + ((size_t)b * HW_ + px0 + (lane ^ (b & 7))) * 16;
        dA[t] = b * 1024 + lane * 16;
    }
    const float* srcM[2][2];
    int dM[2][2];
#pragma unroll
    for (int u = 0; u < 2; ++u)
#pragma unroll
        for (int kq = 0; kq < 2; ++kq) {
            int m = w * 2 + u;
            int k = kq * 4 + (lane >> 4);
            int g = (lane & 15) ^ m;
            srcM[u][kq] = mm + ((size_t)(m0 + m) * KF_ + k) * HW_ + px0 + g * 4;
            dM[u][kq] = m * 2048 + kq * 1024 + lane * 16;
        }

    auto stage = [&](int s) {
        unsigned char* base = L + (size_t)(s & 1) * 65536;
#pragma unroll
        for (int t = 0; t < 4; ++t)
            gl2lds16(srcA[t] + (size_t)(s >> 1) * 1605632 + (s & 1) * 8, base + dA[t]);
#pragma unroll
        for (int u = 0; u < 2; ++u)
#pragma unroll
            for (int kq = 0; kq < 2; ++kq)
                gl2lds16(srcM[u][kq] + (size_t)s * 8 * HW_, base + 32768 + dM[u][kq]);
    };

    short8 fA[8], fb0[8], fb1[8];
    floatx4 acc0[8] = {}, acc1[8] = {};
    float csp[8] = {0.f, 0.f, 0.f, 0.f, 0.f, 0.f, 0.f, 0.f};

    stage(0);

#pragma unroll 4
    for (int s = 0; s < 64; ++s) {
        __builtin_amdgcn_s_barrier();   // WAR
        if (s < 63) {
            stage(s + 1);
            asm volatile("s_waitcnt vmcnt(8)" ::: "memory");
        } else {
            asm volatile("s_waitcnt vmcnt(0)" ::: "memory");
        }
        __builtin_amdgcn_sched_barrier(0);
        __builtin_amdgcn_s_barrier();   // RAW
        const unsigned char* ab = L + (size_t)(s & 1) * 65536;
        const unsigned char* mb = ab + 32768;
        int rq = s & 3;
        if (q == rq) {
#pragma unroll
            for (int e = 0; e < 8; ++e) {
                int p = w8 + e;
                int slotA = (p ^ (li & 7)) * 16;
                fb0[e] = *(const short8*)(ab + li * 1024 + slotA);
                fb1[e] = *(const short8*)(ab + (16 + li) * 1024 + slotA);
                const unsigned char* mrow = mb + li * 2048 +
                                            ((((p >> 2) ^ li) & 15) * 16) + (p & 3) * 4;
                short8 pk;
                float cs = 0.f;
#pragma unroll
                for (int k = 0; k < 8; ++k) {
                    float x = *(const float*)(mrow + k * 256);
                    x = fminf(fmaxf(x, 0.f), 1.f);
                    cs += x;
                    pk[k] = (short)f2bf(x);
                }
                csp[e] += cs;
                fA[e] = pk;
            }
        }
        if (rq == 3) {
#pragma unroll
            for (int e = 0; e < 8; ++e) {
                acc0[e] = __builtin_amdgcn_mfma_f32_16x16x32_bf16(fA[e], fb0[e], acc0[e], 0, 0, 0);
                acc1[e] = __builtin_amdgcn_mfma_f32_16x16x32_bf16(fA[e], fb1[e], acc1[e], 0, 0, 0);
            }
        }
    }

    // csum: reduce over the 4 q-groups (each held distinct k-octets)
#pragma unroll
    for (int e = 0; e < 8; ++e) {
        float v = csp[e];
        v += __shfl_xor(v, 16);
        v += __shfl_xor(v, 32);
        if (q == 0) csum_s[li * 64 + w8 + e] = v;
    }
    __syncthreads();

    // epilogue: log, bg-max, sum over px
#pragma unroll
    for (int bf = 0; bf < 2; ++bf) {
        int b = bf * 16 + li;
#pragma unroll
        for (int r = 0; r < 4; ++r) {
            int ml = q * 4 + r;
            float sacc = 0.f;
#pragma unroll
            for (int e = 0; e < 8; ++e) {
                int p = w8 + e;
                float inv = 1.f / fmaxf(csum_s[ml * 64 + p], 1e-12f);
                float a = (bf == 0) ? acc0[e][r] : acc1[e][r];
                sacc += fmaxf(logf(a * inv * 0.4f + 1e-10f), bgs[b * 64 + p]);
            }
            atomicAdd(&pms[ml * 32 + b], sacc);
        }
    }
    __syncthreads();
    {
        int ml = tid >> 5, b = tid & 31;
        atomicAdd(&pm[(size_t)b * KM_ + m0 + ml], pms[tid]);
    }
}

// ---- K5: scores -> mix_likeli -> softmax
__global__ __launch_bounds__(64) void final_kernel(const float* __restrict__ pm,
                                                   float* __restrict__ out_soft,
                                                   float* __restrict__ out_ml) {
    int b = threadIdx.x;
    if (b >= B_) return;
    float ml[12];
#pragma unroll
    for (int c = 0; c < 12; ++c) {
        float s = -1e30f;
#pragma unroll
        for (int j = 0; j < 4; ++j) s = fmaxf(s, pm[(size_t)b * KM_ + c * 4 + j]);
        ml[c] = s / (float)HW_;
    }
    float z[12], zs = 0.f;
#pragma unroll
    for (int c = 0; c < 12; ++c) {
        float e = fminf(fmaxf(ml[c] * 2.f, -88.7f), 88.7f);
        z[c] = expf(e); zs += z[c];
    }
#pragma unroll
    for (int c = 0; c < 12; ++c) {
        out_soft[(size_t)b * 12 + c] = z[c] / zs;
        out_ml[(size_t)b * 12 + c] = ml[c];
    }
}

extern "C" void kernel_launch(void* const* d_in, const int* in_sizes, int n_in,
                              void* d_out, int out_size, void* d_ws, size_t ws_size,
                              hipStream_t stream) {
    const float* vgg = (const float*)d_in[0];
    const float* cw  = (const float*)d_in[1];
    const float* mmp = (const float*)d_in[2];
    const float* cl  = (const float*)d_in[3];
    float* out = (float*)d_out;
    char* ws = (char*)d_ws;

    unsigned short* wn   = (unsigned short*)(ws);              // 524288
    float* ck            = (float*)(ws + 524288);              // 10240
    float* invn          = (float*)(ws + 534528);              // 401408
    float* pm            = (float*)(ws + 935936);              // 6144
    float* bgacc         = (float*)(ws + 942080);              // 3211264
    unsigned short* xnt  = (unsigned short*)(ws + 4153344);    // 102760448
    const size_t ACT_OFF = 4153344 + 102760448;                // 106913792
    const size_t ACT_BYTES = (size_t)B_ * HW_ * KF_ * 2;       // 102760448

    int act_in_ws = (ws_size >= ACT_OFF + ACT_BYTES) ? 1 : 0;
    unsigned short* act = act_in_ws ? (unsigned short*)(ws + ACT_OFF)
                                    : (unsigned short*)(out + 384);

    hipMemsetAsync(pm, 0, (size_t)B_ * KM_ * sizeof(float), stream);
    hipMemsetAsync(bgacc, 0, (size_t)B_ * HW_ * 8 * sizeof(float), stream);
    prep_kernel<<<dim3(KF_ + NCL_), dim3(64), 0, stream>>>(cw, cl, wn, ck);
    xprep_kernel<<<dim3(49, 32), dim3(512), 0, stream>>>(vgg, xnt, invn, out + 384, act_in_ws);
    gemm_act_kernel<<<dim3(3136), dim3(512), 0, stream>>>(xnt, wn, invn, ck, act, bgacc);
    fg3_kernel<<<dim3(168), dim3(512), 0, stream>>>(act, mmp, bgacc, pm);
    final_kernel<<<1, 64, 0, stream>>>(pm, out, out + 384 + (size_t)B_ * C_ * HW_);
    if (!act_in_ws)
        hipMemcpyAsync(out + 384, vgg, (size_t)B_ * C_ * HW_ * sizeof(float),
                       hipMemcpyDeviceToDevice, stream);
}

// Round 12
// 402.063 us; speedup vs baseline: 1.1240x; 1.1240x over previous
//
#include <hip/hip_runtime.h>

#define B_ 32
#define C_ 512
#define HW_ 3136
#define KF_ 512
#define KM_ 48
#define NCL_ 5

typedef __attribute__((ext_vector_type(8))) short short8;
typedef __attribute__((ext_vector_type(4))) short short4v;
typedef __attribute__((ext_vector_type(4))) float floatx4;
typedef unsigned int u32;
typedef u32 __attribute__((address_space(1))) gu32;
typedef u32 __attribute__((address_space(3))) lu32;

__device__ __forceinline__ unsigned short f2bf(float f) {
    union { float f; unsigned u; } v; v.f = f;
    unsigned r = v.u + 0x7FFFu + ((v.u >> 16) & 1u);
    return (unsigned short)(r >> 16);
}
__device__ __forceinline__ void gl2lds16(const void* g, void* l) {
    __builtin_amdgcn_global_load_lds((const gu32*)g, (lu32*)l, 16, 0, 0);
}

// ---- K0: normalize conv weights -> bf16 wn; clutter -> ck fp32 (clip + L1)
__global__ __launch_bounds__(64) void prep_kernel(const float* __restrict__ w,
                                                  const float* __restrict__ cl,
                                                  unsigned short* __restrict__ wn,
                                                  float* __restrict__ ck) {
    int bid = blockIdx.x, t = threadIdx.x;
    if (bid < KF_) {
        const float* row = w + (size_t)bid * C_;
        float ss = 0.f;
        float x[8];
#pragma unroll
        for (int j = 0; j < 8; ++j) { x[j] = row[t * 8 + j]; ss += x[j] * x[j]; }
        for (int m = 32; m >= 1; m >>= 1) ss += __shfl_xor(ss, m);
        float inv = 1.f / sqrtf(ss);
#pragma unroll
        for (int j = 0; j < 8; ++j) wn[(size_t)bid * C_ + t * 8 + j] = f2bf(x[j] * inv);
    } else {
        int n = bid - KF_;
        if (n >= NCL_) return;
        const float* row = cl + (size_t)n * KF_;
        float s = 0.f;
        float v[8];
#pragma unroll
        for (int j = 0; j < 8; ++j) {
            float x = row[t * 8 + j];
            x = fminf(fmaxf(x, 0.f), 1.f);
            v[j] = x; s += x;
        }
        for (int m = 32; m >= 1; m >>= 1) s += __shfl_xor(s, m);
        float inv = 1.f / fmaxf(s, 1e-12f);
#pragma unroll
        for (int j = 0; j < 8; ++j) ck[(size_t)n * KF_ + t * 8 + j] = v[j] * inv;
    }
}

// ---- K1: streaming pass: vgg -> xnt (raw bf16, [b*HW+p][c]), invn, vgg copy
__global__ __launch_bounds__(512) void xprep_kernel(const float* __restrict__ vgg,
                                                    unsigned short* __restrict__ xnt,
                                                    float* __restrict__ invn,
                                                    float* __restrict__ out_vgg,
                                                    int write_vgg) {
    int pt = blockIdx.x, b = blockIdx.y;
    int tid = threadIdx.x;
    int px = tid & 63, cq = tid >> 6;
    __shared__ __align__(16) unsigned short tile[64][512];
    __shared__ float ssp[8][64];
    const float* vcol = vgg + (size_t)b * C_ * HW_ + pt * 64 + px;
    float* ovcol = out_vgg + (size_t)b * C_ * HW_ + pt * 64 + px;

    float ss = 0.f;
#pragma unroll
    for (int j = 0; j < 16; ++j) {
        int c0 = cq * 64 + j * 4;
        float x0 = vcol[(size_t)(c0 + 0) * HW_];
        float x1 = vcol[(size_t)(c0 + 1) * HW_];
        float x2 = vcol[(size_t)(c0 + 2) * HW_];
        float x3 = vcol[(size_t)(c0 + 3) * HW_];
        ss += x0 * x0 + x1 * x1 + x2 * x2 + x3 * x3;
        short4v pk;
        pk[0] = (short)f2bf(x0); pk[1] = (short)f2bf(x1);
        pk[2] = (short)f2bf(x2); pk[3] = (short)f2bf(x3);
        *(short4v*)&tile[px][c0] = pk;
        if (write_vgg) {
            ovcol[(size_t)(c0 + 0) * HW_] = x0;
            ovcol[(size_t)(c0 + 1) * HW_] = x1;
            ovcol[(size_t)(c0 + 2) * HW_] = x2;
            ovcol[(size_t)(c0 + 3) * HW_] = x3;
        }
    }
    ssp[cq][px] = ss;
    __syncthreads();
    if (tid < 64) {
        float s = 0.f;
#pragma unroll
        for (int q = 0; q < 8; ++q) s += ssp[q][tid];
        float n = sqrtf(s);
        invn[(size_t)b * HW_ + pt * 64 + tid] = (n == 0.f) ? 1.f : 1.f / n;
    }
    __syncthreads();
    int row = tid >> 3, ch = tid & 7;
    unsigned short* orow = xnt + ((size_t)b * HW_ + pt * 64 + row) * 512;
#pragma unroll
    for (int j = 0; j < 8; ++j) {
        int c8 = (ch + 8 * j) * 8;
        *(short8*)(orow + c8) = *(const short8*)&tile[row][c8];
    }
}

// ---- K2: GEMM act = exp(30*(xnt.wn)*invn), counted-vmcnt dbuf + bg partials.
__global__ __launch_bounds__(512) void gemm_act_kernel(const unsigned short* __restrict__ xnt,
                                                       const unsigned short* __restrict__ wn,
                                                       const float* __restrict__ invn,
                                                       const float* __restrict__ ck,
                                                       unsigned short* __restrict__ act,
                                                       float* __restrict__ bgacc) {
    int wg = blockIdx.x;
    int swz = (wg & 7) * 392 + (wg >> 3);   // 3136 = 8*392, bijective
    int pt = swz >> 2, ft = swz & 3;
    int tid = threadIdx.x, lane = tid & 63;
    int wid = tid >> 6;
    int li = lane & 15, q = lane >> 4;
    int wm = wid & 1, wq = wid >> 1;

    __shared__ __align__(16) unsigned short a_lds[2][128 * 64];
    __shared__ __align__(16) unsigned short b_lds[2][128 * 64];
    __shared__ float inv_l[128];
    __shared__ float ck_l[NCL_ * KF_];
    __shared__ float bga_l[128 * NCL_];
    if (tid < 128) inv_l[tid] = invn[(size_t)pt * 128 + tid];
    for (int i = tid; i < NCL_ * KF_; i += 512) ck_l[i] = ck[i];
    for (int i = tid; i < 128 * NCL_; i += 512) bga_l[i] = 0.f;

    const unsigned short* ga = wn + ((size_t)ft * 128 + (tid >> 3)) * 512 + (tid & 7) * 8;
    const unsigned short* gb = xnt + ((size_t)pt * 128 + (tid >> 3)) * 512 + (tid & 7) * 8;
    int ldst = tid * 8;

    floatx4 acc[4][2] = {};

#pragma unroll
    for (int i = 0; i < 2; ++i) {
        gl2lds16(ga + (size_t)i * 64 * 512, &a_lds[0][ldst + i * 4096]);
        gl2lds16(gb + (size_t)i * 64 * 512, &b_lds[0][ldst + i * 4096]);
    }

#pragma unroll 1
    for (int s = 0; s < 8; ++s) {
        __builtin_amdgcn_s_barrier();   // WAR
        if (s < 7) {
            int nb = (s + 1) & 1;
#pragma unroll
            for (int i = 0; i < 2; ++i) {
                gl2lds16(ga + (size_t)i * 64 * 512 + (s + 1) * 64, &a_lds[nb][ldst + i * 4096]);
                gl2lds16(gb + (size_t)i * 64 * 512 + (s + 1) * 64, &b_lds[nb][ldst + i * 4096]);
            }
            asm volatile("s_waitcnt vmcnt(4)" ::: "memory");
        } else {
            asm volatile("s_waitcnt vmcnt(0)" ::: "memory");
        }
        __builtin_amdgcn_sched_barrier(0);
        __builtin_amdgcn_s_barrier();   // RAW
        int buf = s & 1;
#pragma unroll
        for (int k2 = 0; k2 < 2; ++k2) {
            short8 af[4], bfr[2];
#pragma unroll
            for (int i = 0; i < 4; ++i)
                af[i] = *(const short8*)&a_lds[buf][(wm * 64 + i * 16 + li) * 64 + k2 * 32 + q * 8];
#pragma unroll
            for (int j = 0; j < 2; ++j)
                bfr[j] = *(const short8*)&b_lds[buf][(wq * 32 + j * 16 + li) * 64 + k2 * 32 + q * 8];
#pragma unroll
            for (int i = 0; i < 4; ++i)
#pragma unroll
                for (int j = 0; j < 2; ++j)
                    acc[i][j] = __builtin_amdgcn_mfma_f32_16x16x32_bf16(af[i], bfr[j], acc[i][j], 0, 0, 0);
        }
    }

    // epilogue: scale, exp, store act; bg partials via ck-dot
#pragma unroll
    for (int j = 0; j < 2; ++j) {
        int px = wq * 32 + j * 16 + li;
        float inv = inv_l[px];
        size_t row_g = (size_t)pt * 128 + px;
        float bp[NCL_] = {0.f, 0.f, 0.f, 0.f, 0.f};
#pragma unroll
        for (int i = 0; i < 4; ++i) {
            int chn = ft * 8 + wm * 4 + i;
            int f_g = ft * 128 + wm * 64 + i * 16 + q * 4;
            short4v pk;
            float av[4];
#pragma unroll
            for (int r = 0; r < 4; ++r) {
                float cv = acc[i][j][r] * inv;
                float a = cv > 0.f ? __expf(30.f * cv) : 0.f;
                av[r] = a;
                pk[r] = (short)f2bf(a);
            }
            *(short4v*)(act + ((size_t)chn * 100352 + row_g) * 16 + q * 4) = pk;
#pragma unroll
            for (int n = 0; n < NCL_; ++n)
                bp[n] += av[0] * ck_l[n * KF_ + f_g] + av[1] * ck_l[n * KF_ + f_g + 1] +
                         av[2] * ck_l[n * KF_ + f_g + 2] + av[3] * ck_l[n * KF_ + f_g + 3];
        }
#pragma unroll
        for (int n = 0; n < NCL_; ++n) {
            float v = bp[n];
            v += __shfl_xor(v, 16);
            v += __shfl_xor(v, 32);
            if (q == 0) atomicAdd(&bga_l[px * NCL_ + n], v);
        }
    }
    __syncthreads();
    if (tid < 128) {
        size_t row_g = (size_t)pt * 128 + tid;
#pragma unroll
        for (int n = 0; n < NCL_; ++n)
            atomicAdd(&bgacc[row_g * 8 + n], bga_l[tid * NCL_ + n]);
    }
}

// ---- K4 v5 (fg4): reg-staged, swizzled-LDS per-pixel batched GEMM.
// grid 588 = 98 pt(32px) x 3 mg(16m) x 2 bh(16b), XCD-bijective.
// 512 thr / 8 waves (wave = 4 px). 32 stages of K16; MFMA(16x16x32) via
// 2-stage q-parity. LDS 69 KB -> 2 blocks/CU.
#define FG4_MML 0          // 2 x 16384  (mm bf16 [m16][px'32][k16])
#define FG4_ACTL 32768     // 2 x 16384  (act bf16 [b16][px'32][k16])
#define FG4_BGS 65536      // [b16][px32] f32
#define FG4_CSUM 67584     // [m16][px32] f32
#define FG4_PMS 69632      // [m16][b16] f32
__global__ __launch_bounds__(512, 4) void fg4_kernel(const unsigned short* __restrict__ act,
                                                     const float* __restrict__ mm,
                                                     const float* __restrict__ bgacc,
                                                     float* __restrict__ pm) {
    __shared__ __align__(16) unsigned char L[70656];
    float* bgs    = (float*)(L + FG4_BGS);
    float* csum_s = (float*)(L + FG4_CSUM);
    float* pms    = (float*)(L + FG4_PMS);

    int bid = blockIdx.x;
    int xcd = bid & 7, pos = bid >> 3;
    int linear = (xcd < 4 ? xcd * 74 : 296 + (xcd - 4) * 73) + pos;  // bijective, 588=8q+4
    int pt = linear / 6, sub = linear - pt * 6;
    int mg = sub >> 1, bh = sub & 1;
    int p0 = pt * 32, m0 = mg * 16, b0 = bh * 16;

    int tid = threadIdx.x;
    int lane = tid & 63, w = tid >> 6;
    int li = lane & 15, q = lane >> 4;

    if (tid < 256) pms[tid] = 0.f;
    csum_s[tid] = 0.f;
    {
        int b = tid >> 5, px = tid & 31;
        const float* bgp = bgacc + ((size_t)(b0 + b) * HW_ + p0 + px) * 8;
        float mx = -1e30f;
#pragma unroll
        for (int n = 0; n < NCL_; ++n) mx = fmaxf(mx, logf(bgp[n] * 0.6f + 1e-10f));
        bgs[b * 32 + px] = mx;
    }

    // staging roles
    int ab = tid >> 5, apx = tid & 31;                       // act: b-sub, px
    int mmM = tid >> 5, mkq = (tid >> 3) & 3, mpxg = tid & 7; // mm: m, k-quad, px-group(4)
    const unsigned short* aSrc = act + ((size_t)(b0 + ab) * HW_ + p0 + apx) * 16;
    const float* mSrc = mm + ((size_t)(m0 + mmM) * KF_ + mkq * 4) * HW_ + p0 + mpxg * 4;
    unsigned char* aW = L + FG4_ACTL + ab * 1024 + ((apx ^ (ab & 3)) * 32);

    floatx4 mr[4];
    short8 ar[2];
    float cs[4] = {0.f, 0.f, 0.f, 0.f};
    floatx4 acc[4] = {};
    short8 fa[4], fb[4];   // fragment halves held across the 2-stage parity

    auto loadRegs = [&](int s) {
#pragma unroll
        for (int j = 0; j < 4; ++j)
            mr[j] = *(const floatx4*)(mSrc + ((size_t)s * 16 + j) * HW_);
        const unsigned short* as = aSrc + (size_t)s * 1605632;
        ar[0] = *(const short8*)(as);
        ar[1] = *(const short8*)(as + 8);
    };
    auto cvtWrite = [&](int s) {
        int buf = (s & 1) * 16384;
        // mm: transpose 4k x 4px in regs -> bf16x4 b64 writes, accumulate csum
#pragma unroll
        for (int i = 0; i < 4; ++i) {
            int px = mpxg * 4 + i;
            float x0 = fminf(fmaxf(mr[0][i], 0.f), 1.f);
            float x1 = fminf(fmaxf(mr[1][i], 0.f), 1.f);
            float x2 = fminf(fmaxf(mr[2][i], 0.f), 1.f);
            float x3 = fminf(fmaxf(mr[3][i], 0.f), 1.f);
            cs[i] += x0 + x1 + x2 + x3;
            short4v pk;
            pk[0] = (short)f2bf(x0); pk[1] = (short)f2bf(x1);
            pk[2] = (short)f2bf(x2); pk[3] = (short)f2bf(x3);
            *(short4v*)(L + FG4_MML + buf + mmM * 1024 + ((px ^ (mmM & 3)) * 32) + mkq * 8) = pk;
        }
        // act: 32B contiguous k-row
        *(short8*)(aW + buf) = ar[0];
        *(short8*)(aW + buf + 16) = ar[1];
    };

    loadRegs(0);
    cvtWrite(0);
    loadRegs(1);
    __syncthreads();

#pragma unroll 2
    for (int s = 0; s < 32; ++s) {
        // compute from buf s&1: parity fragment reads + MFMA every 2nd stage
        const unsigned char* bufM = L + FG4_MML + (s & 1) * 16384;
        const unsigned char* bufA = L + FG4_ACTL + (s & 1) * 16384;
        if ((q >> 1) == (s & 1)) {
#pragma unroll
            for (int e = 0; e < 4; ++e) {
                int px = w * 4 + e;
                int off = li * 1024 + ((px ^ (li & 3)) * 32) + (q & 1) * 16;
                fa[e] = *(const short8*)(bufM + off);
                fb[e] = *(const short8*)(bufA + off);
            }
        }
        if (s & 1) {
#pragma unroll
            for (int e = 0; e < 4; ++e)
                acc[e] = __builtin_amdgcn_mfma_f32_16x16x32_bf16(fa[e], fb[e], acc[e], 0, 0, 0);
        }
        if (s < 31) {
            cvtWrite(s + 1);
            if (s < 30) loadRegs(s + 2);
        }
        __syncthreads();
    }

    // csum finalize
#pragma unroll
    for (int i = 0; i < 4; ++i)
        atomicAdd(&csum_s[mmM * 32 + mpxg * 4 + i], cs[i]);
    __syncthreads();

    // epilogue: log, bg-max, sum over the wave's 4 px
#pragma unroll
    for (int r = 0; r < 4; ++r) {
        int m = q * 4 + r;
        float sacc = 0.f;
#pragma unroll
        for (int e = 0; e < 4; ++e) {
            int px = w * 4 + e;
            float inv = 1.f / fmaxf(csum_s[m * 32 + px], 1e-12f);
            float v = fmaxf(logf(acc[e][r] * inv * 0.4f + 1e-10f), bgs[li * 32 + px]);
            sacc += v;
        }
        atomicAdd(&pms[m * 16 + li], sacc);
    }
    __syncthreads();
    if (tid < 256) {
        int m = tid >> 4, b = tid & 15;
        atomicAdd(&pm[(size_t)(b0 + b) * KM_ + m0 + m], pms[m * 16 + b]);
    }
}

// ---- K5: scores -> mix_likeli -> softmax
__global__ __launch_bounds__(64) void final_kernel(const float* __restrict__ pm,
                                                   float* __restrict__ out_soft,
                                                   float* __restrict__ out_ml) {
    int b = threadIdx.x;
    if (b >= B_) return;
    float ml[12];
#pragma unroll
    for (int c = 0; c < 12; ++c) {
        float s = -1e30f;
#pragma unroll
        for (int j = 0; j < 4; ++j) s = fmaxf(s, pm[(size_t)b * KM_ + c * 4 + j]);
        ml[c] = s / (float)HW_;
    }
    float z[12], zs = 0.f;
#pragma unroll
    for (int c = 0; c < 12; ++c) {
        float e = fminf(fmaxf(ml[c] * 2.f, -88.7f), 88.7f);
        z[c] = expf(e); zs += z[c];
    }
#pragma unroll
    for (int c = 0; c < 12; ++c) {
        out_soft[(size_t)b * 12 + c] = z[c] / zs;
        out_ml[(size_t)b * 12 + c] = ml[c];
    }
}

extern "C" void kernel_launch(void* const* d_in, const int* in_sizes, int n_in,
                              void* d_out, int out_size, void* d_ws, size_t ws_size,
                              hipStream_t stream) {
    const float* vgg = (const float*)d_in[0];
    const float* cw  = (const float*)d_in[1];
    const float* mmp = (const float*)d_in[2];
    const float* cl  = (const float*)d_in[3];
    float* out = (float*)d_out;
    char* ws = (char*)d_ws;

    unsigned short* wn   = (unsigned short*)(ws);              // 524288
    float* ck            = (float*)(ws + 524288);              // 10240
    float* invn          = (float*)(ws + 534528);              // 401408
    float* pm            = (float*)(ws + 935936);              // 6144
    float* bgacc         = (float*)(ws + 942080);              // 3211264
    unsigned short* xnt  = (unsigned short*)(ws + 4153344);    // 102760448
    const size_t ACT_OFF = 4153344 + 102760448;                // 106913792
    const size_t ACT_BYTES = (size_t)B_ * HW_ * KF_ * 2;       // 102760448

    int act_in_ws = (ws_size >= ACT_OFF + ACT_BYTES) ? 1 : 0;
    unsigned short* act = act_in_ws ? (unsigned short*)(ws + ACT_OFF)
                                    : (unsigned short*)(out + 384);

    hipMemsetAsync(pm, 0, (size_t)B_ * KM_ * sizeof(float), stream);
    hipMemsetAsync(bgacc, 0, (size_t)B_ * HW_ * 8 * sizeof(float), stream);
    prep_kernel<<<dim3(KF_ + NCL_), dim3(64), 0, stream>>>(cw, cl, wn, ck);
    xprep_kernel<<<dim3(49, 32), dim3(512), 0, stream>>>(vgg, xnt, invn, out + 384, act_in_ws);
    gemm_act_kernel<<<dim3(3136), dim3(512), 0, stream>>>(xnt, wn, invn, ck, act, bgacc);
    fg4_kernel<<<dim3(588), dim3(512), 0, stream>>>(act, mmp, bgacc, pm);
    final_kernel<<<1, 64, 0, stream>>>(pm, out, out + 384 + (size_t)B_ * C_ * HW_);
    if (!act_in_ws)
        hipMemcpyAsync(out + 384, vgg, (size_t)B_ * C_ * HW_ * sizeof(float),
                       hipMemcpyDeviceToDevice, stream);
}